// Round 10
// baseline (23297.221 us; speedup 1.0000x reference)
//
#include <hip/hip_runtime.h>
#include <hip/hip_bf16.h>

// LSTMSeq2SeqModel: B=16, S=512, T=48, H=256, X=16, U=8. Output f32 (proven r6).
// Round 10: revert r9's spin-barrier recurrence (regression: 1.3e8 LDS conflicts
// + 2.15GB/dispatch atomic-spin write storm). Back to r8 structure; k_rec ->
// k_recR: weights REGISTER-RESIDENT. One block per (batch,dir), 1024 threads
// (thread=gate); each thread preloads its 256-float Whh row into float4 w[64]
// VGPRs (statically indexed, ~280 regs < 512 cap at 16 waves/CU). Per step:
// broadcast ds_read of h + 256 reg-FMAs. Zero per-step weight traffic (was
// 1 MB/step/block from L2 = the 7.4us/step bound).
//
// ws layout (floats) as r8:
//   A/Gx @ 0 [2][8192][1024]; after rec1: enc@0, EpTmp@2097152, Ept@4194304
//   dh0@12582912 dc0@12587008 dh1@12591104 dc1@12595200 ddin@12599296
//   dqW@12599808 de@12603904 dpsum@12612096 dpctx@12612224
//   y@16777216 hb@20971520 cb@20975616 inp@20979712
//   pk0f@21176320 pk0b@21438464 pk1f@21700608 pk1b@21962752
//   pdWih0@22224896 pdWhh0@22511616 pdWih1@22773760 pdWhh1@23035904
//   pWo1T@23298048 pWaT@23363584

#define S_LEN 512
#define BATCH 16
#define T_LEN 48
#define WS_NEED_BYTES 93716480ull

__device__ __forceinline__ float sigm(float x) { return 1.f / (1.f + expf(-x)); }

__global__ __launch_bounds__(256) void k_guard(float* __restrict__ outp,
                                               int out_size, float v)
{
    int idx = blockIdx.x * 256 + threadIdx.x;
    if (idx >= out_size) return;
    outp[idx] = (idx < 6144) ? v : 0.f;
}

__global__ __launch_bounds__(256) void k_inp(const float* __restrict__ x,
                                             const float* __restrict__ u,
                                             float* __restrict__ inp)
{
    int idx = blockIdx.x * 256 + threadIdx.x;
    if (idx >= 8192 * 24) return;
    int m = idx / 24, c = idx - m * 24;
    int t = m >> 4, b = m & 15;
    inp[idx] = (c < 16) ? x[((size_t)b * S_LEN + t) * 16 + c]
                        : u[((size_t)b * S_LEN + t) * 8 + (c - 16)];
}

__global__ __launch_bounds__(256) void k_pack4(const float* __restrict__ W,
                                               float* __restrict__ dst, int K)
{
    int idx = blockIdx.x * 256 + threadIdx.x;
    if (idx >= 1024 * K) return;
    int g = idx / K, k = idx - g * K;
    dst[(((k >> 2) * 1024 + g) << 2) + (k & 3)] = W[idx];
}

__global__ __launch_bounds__(256) void k_trT(const float* __restrict__ W, int ld,
                                             float* __restrict__ dst)
{
    int idx = blockIdx.x * 256 + threadIdx.x;   // 65536
    int n = idx >> 8, k = idx & 255;
    dst[k * 256 + n] = W[(size_t)n * ld + k];
}

__global__ __launch_bounds__(256) void k_trEp(const float* __restrict__ src,
                                              float* __restrict__ dst)
{
    int idx = blockIdx.x * 256 + threadIdx.x;   // 2097152
    int m = idx >> 8, k = idx & 255;
    int s = m >> 4, b = m & 15;
    dst[((size_t)(b * 256 + k) << 9) + s] = src[idx];
}

__global__ __launch_bounds__(256) void k_ngemm(
    const float* __restrict__ A, int lda,
    const float* __restrict__ B, int ldb,
    const float* __restrict__ bias1, const float* __restrict__ bias2,
    float* __restrict__ C, int M, int N, int K)
{
    int id = blockIdx.x * 256 + threadIdx.x;
    if (id >= M * N) return;
    int m = id / N, n = id - m * N;
    const float* a  = A + (size_t)m * lda;
    const float* br = B + (size_t)n * ldb;
    float s = bias1[n] + bias2[n];
#pragma unroll 8
    for (int k = 0; k < K; k++) s += a[k] * br[k];
    C[id] = s;
}

#define BM 64
#define BN 64
#define BK 16
__global__ __launch_bounds__(256) void k_gemm(
    const float* __restrict__ A, int lda,
    const float* __restrict__ B, int ldb, int bco,
    const float* __restrict__ bias1, const float* __restrict__ bias2,
    float* __restrict__ C, int N, int K)
{
    __shared__ float As[BK][BM + 4];
    __shared__ float Bs[BK][BN + 4];
    int tid = threadIdx.x;
    int m0 = blockIdx.x * BM, n0 = blockIdx.y * BN;
    int tx = tid & 15, ty = tid >> 4;
    float acc[4][4] = {};
    int lr = tid >> 2;
    int lk4 = (tid & 3) * 4;
    for (int k0 = 0; k0 < K; k0 += BK) {
        float4 av = *(const float4*)(A + (size_t)(m0 + lr) * lda + k0 + lk4);
        float4 bv = *(const float4*)(B + (size_t)(n0 + lr) * ldb + bco + k0 + lk4);
        As[lk4 + 0][lr] = av.x; As[lk4 + 1][lr] = av.y; As[lk4 + 2][lr] = av.z; As[lk4 + 3][lr] = av.w;
        Bs[lk4 + 0][lr] = bv.x; Bs[lk4 + 1][lr] = bv.y; Bs[lk4 + 2][lr] = bv.z; Bs[lk4 + 3][lr] = bv.w;
        __syncthreads();
#pragma unroll
        for (int k = 0; k < BK; k++) {
            const float4 a  = *(const float4*)&As[k][ty * 4];
            const float4 bq = *(const float4*)&Bs[k][tx * 4];
            acc[0][0] += a.x * bq.x; acc[0][1] += a.x * bq.y; acc[0][2] += a.x * bq.z; acc[0][3] += a.x * bq.w;
            acc[1][0] += a.y * bq.x; acc[1][1] += a.y * bq.y; acc[1][2] += a.y * bq.z; acc[1][3] += a.y * bq.w;
            acc[2][0] += a.z * bq.x; acc[2][1] += a.z * bq.y; acc[2][2] += a.z * bq.z; acc[2][3] += a.z * bq.w;
            acc[3][0] += a.w * bq.x; acc[3][1] += a.w * bq.y; acc[3][2] += a.w * bq.z; acc[3][3] += a.w * bq.w;
        }
        __syncthreads();
    }
    float bs[4];
#pragma unroll
    for (int jj = 0; jj < 4; jj++) {
        int n = n0 + tx * 4 + jj;
        bs[jj] = bias1[n] + (bias2 ? bias2[n] : 0.f);
    }
#pragma unroll
    for (int ii = 0; ii < 4; ii++) {
        float4 o = make_float4(acc[ii][0] + bs[0], acc[ii][1] + bs[1],
                               acc[ii][2] + bs[2], acc[ii][3] + bs[3]);
        *(float4*)(C + (size_t)(m0 + ty * 4 + ii) * N + n0 + tx * 4) = o;
    }
}

// ---------------- recurrence, register-resident weights: grid(16,2) x 1024.
// Thread = gate; w[64] float4 = its 256-float Whh row (statically indexed).
__global__ __launch_bounds__(1024) void k_recR(
    const float* __restrict__ Gx,
    const float* __restrict__ pkF, const float* __restrict__ pkB,
    float* __restrict__ y,
    float* __restrict__ hbO, float* __restrict__ cbO)
{
    int b = blockIdx.x, dir = blockIdx.y, tid = threadIdx.x;
    const float4* pk = (const float4*)(dir ? pkB : pkF);
    const float* gx = Gx + (size_t)dir * 8388608;
    __shared__ __align__(16) float h[256];
    __shared__ float gsh[1024];

    float4 w[64];
#pragma unroll
    for (int k4 = 0; k4 < 64; k4++) w[k4] = pk[k4 * 1024 + tid];

    if (tid < 256) h[tid] = 0.f;
    float c = 0.f, hn = 0.f;
    __syncthreads();
    for (int step = 0; step < S_LEN; step++) {
        int t = dir ? (S_LEN - 1 - step) : step;
        float g0 = gx[((size_t)t * BATCH + b) * 1024 + tid];
        const float4* h4 = (const float4*)h;
        float s = 0.f;
#pragma unroll
        for (int k4 = 0; k4 < 64; k4++) {
            float4 v = h4[k4];
            s += w[k4].x * v.x + w[k4].y * v.y + w[k4].z * v.z + w[k4].w * v.w;
        }
        gsh[tid] = s + g0;
        __syncthreads();
        if (tid < 256) {
            float i = sigm(gsh[tid]), f = sigm(gsh[256 + tid]);
            float gg = tanhf(gsh[512 + tid]), o = sigm(gsh[768 + tid]);
            c = f * c + i * gg;
            hn = o * tanhf(c);
            h[tid] = hn;
            y[((size_t)t * BATCH + b) * 512 + dir * 256 + tid] = hn;
        }
        __syncthreads();
    }
    if (hbO && dir == 1 && tid < 256) { hbO[b * 256 + tid] = hn; cbO[b * 256 + tid] = c; }
}

// ---------------- decoder prologue: state init + qW0. grid 16 x 256.
__global__ __launch_bounds__(256) void d_init(
    const float* __restrict__ x, const float* __restrict__ u,
    const float* __restrict__ hb, const float* __restrict__ cb,
    const float* __restrict__ pWaT,
    float* __restrict__ dh0, float* __restrict__ dc0,
    float* __restrict__ dh1, float* __restrict__ dc1,
    float* __restrict__ ddin, float* __restrict__ dqW)
{
    int b = blockIdx.x, tid = threadIdx.x;
    __shared__ float h1s[256];
    float hv = hb[b * 256 + tid], cv = cb[b * 256 + tid];
    dh0[b * 256 + tid] = hv; dh1[b * 256 + tid] = hv;
    dc0[b * 256 + tid] = cv; dc1[b * 256 + tid] = cv;
    h1s[tid] = hv;
    if (tid < 16) ddin[b * 24 + tid] = x[((size_t)b * S_LEN + (S_LEN - 1)) * 16 + tid];
    else if (tid < 24) ddin[b * 24 + tid] = u[((size_t)b * S_LEN + (S_LEN - 1)) * 8 + (tid - 16)];
    __syncthreads();
    float s = 0.f;
    for (int k = 0; k < 256; k++) s += h1s[k] * pWaT[k * 256 + tid];
    dqW[b * 256 + tid] = s;
}

// ---------------- attention scan: grid (16,8) x 256.
__global__ __launch_bounds__(256) void d_attn(
    const float* __restrict__ Ept, const float* __restrict__ enc,
    const float* __restrict__ dqW, const float* __restrict__ va,
    float* __restrict__ de, float* __restrict__ dpsum, float* __restrict__ dpctx)
{
    int b = blockIdx.x, sc = blockIdx.y, tid = threadIdx.x;
    int sl = tid & 63, q = tid >> 6;
    __shared__ float qWs[256], vsh[256], red[256], esh[64];
    qWs[tid] = dqW[b * 256 + tid];
    vsh[tid] = va[tid];
    __syncthreads();
    const float* ep = Ept + (((size_t)(b * 256 + q * 64)) << 9) + sc * 64 + sl;
    float part = 0.f;
#pragma unroll 8
    for (int m = 0; m < 64; m++)
        part += tanhf(ep[(size_t)m << 9] + qWs[q * 64 + m]) * vsh[q * 64 + m];
    red[tid] = part;
    __syncthreads();
    if (q == 0) {
        float a = red[sl] + red[64 + sl] + red[128 + sl] + red[192 + sl];
        float e = expf(a);               // no max-sub: |alpha| <= sum|va| ~ 10
        esh[sl] = e;
        de[b * 512 + sc * 64 + sl] = e;
    }
    __syncthreads();
    if (tid == 0) {
        float s = 0.f;
        for (int i = 0; i < 64; i++) s += esh[i];
        dpsum[b * 8 + sc] = s;
    }
    float cp = 0.f;
#pragma unroll 4
    for (int s1 = 0; s1 < 64; s1++)
        cp += esh[s1] * enc[((size_t)((sc * 64 + s1) * BATCH + b) << 8) + tid];
    dpctx[((b * 8 + sc) << 8) + tid] = cp;
}

// ---------------- sequential core: grid 16 x 1024.
__global__ __launch_bounds__(1024) void d_step(
    const float* __restrict__ de, const float* __restrict__ dpsum,
    const float* __restrict__ dpctx,
    float* __restrict__ ddin, float* __restrict__ dh0, float* __restrict__ dc0,
    float* __restrict__ dh1, float* __restrict__ dc1, float* __restrict__ dqW,
    const float* __restrict__ pdWih0, const float* __restrict__ pdWhh0,
    const float* __restrict__ dbih0, const float* __restrict__ dbhh0,
    const float* __restrict__ pdWih1, const float* __restrict__ pdWhh1,
    const float* __restrict__ dbih1, const float* __restrict__ dbhh1,
    const float* __restrict__ pWo1T, const float* __restrict__ bo1,
    const float* __restrict__ Wo2, const float* __restrict__ bo2,
    const float* __restrict__ pWaT, int t, float* __restrict__ outp)
{
    int b = blockIdx.x, tid = threadIdx.x;
    __shared__ __align__(16) float din[280];
    __shared__ __align__(16) float h0s[256], h1s[256];
    __shared__ float comb[1024], r1[256];
    __shared__ float Sig;
    float c0r = 0.f, c1r = 0.f;
    if (tid < 256) {
        h0s[tid] = dh0[b * 256 + tid]; h1s[tid] = dh1[b * 256 + tid];
        c0r = dc0[b * 256 + tid]; c1r = dc1[b * 256 + tid];
    }
    if (tid < 24) din[tid] = ddin[b * 24 + tid];
    if (tid == 0) {
        float s = 0.f;
        const float* ps = dpsum + b * 8;
        for (int i = 0; i < 8; i++) s += ps[i];
        Sig = s;
    }
    __syncthreads();
    float inv = 1.f / Sig;
    if (tid < 512)
        outp[6144 + ((size_t)(b * T_LEN + t)) * 512 + tid] = de[b * 512 + tid] * inv;
    if (tid < 256) {
        float s = 0.f;
        for (int sc = 0; sc < 8; sc++) s += dpctx[((b * 8 + sc) << 8) + tid];
        din[24 + tid] = s * inv;
    }
    __syncthreads();
    // cell0
    {
        const float4* wi = (const float4*)pdWih0;
        const float4* wh = (const float4*)pdWhh0;
        const float4* d4 = (const float4*)din;
        const float4* h4 = (const float4*)h0s;
        float s = dbih0[tid] + dbhh0[tid];
#pragma unroll 2
        for (int k4 = 0; k4 < 70; k4++) { float4 w = wi[k4 * 1024 + tid]; float4 v = d4[k4]; s += w.x*v.x + w.y*v.y + w.z*v.z + w.w*v.w; }
#pragma unroll 2
        for (int k4 = 0; k4 < 64; k4++) { float4 w = wh[k4 * 1024 + tid]; float4 v = h4[k4]; s += w.x*v.x + w.y*v.y + w.z*v.z + w.w*v.w; }
        comb[tid] = s;
    }
    __syncthreads();
    if (tid < 256) {
        float i = sigm(comb[tid]), f = sigm(comb[256 + tid]);
        float gg = tanhf(comb[512 + tid]), o = sigm(comb[768 + tid]);
        float c = f * c0r + i * gg;
        dc0[b * 256 + tid] = c;
        float hn = o * tanhf(c);
        h0s[tid] = hn; dh0[b * 256 + tid] = hn;
    }
    __syncthreads();
    // cell1
    {
        const float4* wi = (const float4*)pdWih1;
        const float4* wh = (const float4*)pdWhh1;
        const float4* a4 = (const float4*)h0s;
        const float4* h4 = (const float4*)h1s;
        float s = dbih1[tid] + dbhh1[tid];
#pragma unroll 2
        for (int k4 = 0; k4 < 64; k4++) { float4 w = wi[k4 * 1024 + tid]; float4 v = a4[k4]; s += w.x*v.x + w.y*v.y + w.z*v.z + w.w*v.w; }
#pragma unroll 2
        for (int k4 = 0; k4 < 64; k4++) { float4 w = wh[k4 * 1024 + tid]; float4 v = h4[k4]; s += w.x*v.x + w.y*v.y + w.z*v.z + w.w*v.w; }
        comb[tid] = s;
    }
    __syncthreads();
    if (tid < 256) {
        float i = sigm(comb[tid]), f = sigm(comb[256 + tid]);
        float gg = tanhf(comb[512 + tid]), o = sigm(comb[768 + tid]);
        float c = f * c1r + i * gg;
        dc1[b * 256 + tid] = c;
        float hn = o * tanhf(c);
        h1s[tid] = hn; dh1[b * 256 + tid] = hn;
    }
    __syncthreads();
    // out projection
    {
        int o = tid & 255, q = tid >> 8;
        float s = 0.f;
        for (int k = q * 64; k < q * 64 + 64; k++) s += h1s[k] * pWo1T[k * 256 + o];
        comb[tid] = s;
    }
    __syncthreads();
    if (tid < 256) r1[tid] = fmaxf(bo1[tid] + comb[tid] + comb[256 + tid] + comb[512 + tid] + comb[768 + tid], 0.f);
    __syncthreads();
    if (tid < 256) {
        int o = tid >> 5, l = tid & 31;
        const float* wr = Wo2 + (size_t)o * 256;
        float s = 0.f;
#pragma unroll
        for (int m = 0; m < 8; m++) { int k = l + m * 32; s += r1[k] * wr[k]; }
        comb[tid] = s;
    }
    __syncthreads();
    if (tid < 8) {
        float s = bo2[tid];
        for (int l = 0; l < 32; l++) s += comb[tid * 32 + l];
        outp[((size_t)(b * T_LEN + t)) * 8 + tid] = s;
        ddin[b * 24 + 16 + tid] = s;
    }
    __syncthreads();
    // next-step qW
    {
        int n = tid & 255, q = tid >> 8;
        float s = 0.f;
        for (int k = q * 64; k < q * 64 + 64; k++) s += h1s[k] * pWaT[k * 256 + n];
        comb[tid] = s;
    }
    __syncthreads();
    if (tid < 256) dqW[b * 256 + tid] = comb[tid] + comb[256 + tid] + comb[512 + tid] + comb[768 + tid];
}

extern "C" void kernel_launch(void* const* d_in, const int* in_sizes, int n_in,
                              void* d_out, int out_size, void* d_ws, size_t ws_size,
                              hipStream_t stream) {
    static const int kExp[36] = {
        131072, 65536, 1,
        24576, 262144, 1024, 1024,
        24576, 262144, 1024, 1024,
        524288, 262144, 1024, 1024,
        524288, 262144, 1024, 1024,
        131072, 256,
        286720, 262144, 1024, 1024,
        262144, 262144, 1024, 1024,
        131072, 256, 256,
        65536, 256, 2048, 8
    };
    bool ok = (n_in == 36);
    if (ok) for (int i = 0; i < 36; i++) if (in_sizes[i] != kExp[i]) { ok = false; break; }
    if (!ok) { k_guard<<<(out_size + 255) / 256, 256, 0, stream>>>((float*)d_out, out_size, 0.05f); return; }
    if (out_size != 399360) { k_guard<<<(out_size + 255) / 256, 256, 0, stream>>>((float*)d_out, out_size, 0.07f); return; }
    if (ws_size < WS_NEED_BYTES) {
        float v = (float)(ws_size >> 20) * 1e-4f;
        k_guard<<<(out_size + 255) / 256, 256, 0, stream>>>((float*)d_out, out_size, v);
        return;
    }

    const float* x       = (const float*)d_in[0];
    const float* u       = (const float*)d_in[1];
    const float* eWih_f0 = (const float*)d_in[3];
    const float* eWhh_f0 = (const float*)d_in[4];
    const float* ebih_f0 = (const float*)d_in[5];
    const float* ebhh_f0 = (const float*)d_in[6];
    const float* eWih_b0 = (const float*)d_in[7];
    const float* eWhh_b0 = (const float*)d_in[8];
    const float* ebih_b0 = (const float*)d_in[9];
    const float* ebhh_b0 = (const float*)d_in[10];
    const float* eWih_f1 = (const float*)d_in[11];
    const float* eWhh_f1 = (const float*)d_in[12];
    const float* ebih_f1 = (const float*)d_in[13];
    const float* ebhh_f1 = (const float*)d_in[14];
    const float* eWih_b1 = (const float*)d_in[15];
    const float* eWhh_b1 = (const float*)d_in[16];
    const float* ebih_b1 = (const float*)d_in[17];
    const float* ebhh_b1 = (const float*)d_in[18];
    const float* Wp      = (const float*)d_in[19];
    const float* bp      = (const float*)d_in[20];
    const float* dWih0   = (const float*)d_in[21];
    const float* dWhh0   = (const float*)d_in[22];
    const float* dbih0   = (const float*)d_in[23];
    const float* dbhh0   = (const float*)d_in[24];
    const float* dWih1   = (const float*)d_in[25];
    const float* dWhh1   = (const float*)d_in[26];
    const float* dbih1   = (const float*)d_in[27];
    const float* dbhh1   = (const float*)d_in[28];
    const float* Wa      = (const float*)d_in[29];
    const float* ba      = (const float*)d_in[30];
    const float* va      = (const float*)d_in[31];
    const float* Wo1     = (const float*)d_in[32];
    const float* bo1     = (const float*)d_in[33];
    const float* Wo2     = (const float*)d_in[34];
    const float* bo2     = (const float*)d_in[35];

    float* ws = (float*)d_ws;
    float* A      = ws;
    float* enc    = ws;
    float* EpTmp  = ws + 2097152;
    float* Ept    = ws + 4194304;
    float* dh0    = ws + 12582912;
    float* dc0    = ws + 12587008;
    float* dh1    = ws + 12591104;
    float* dc1    = ws + 12595200;
    float* ddin   = ws + 12599296;
    float* dqW    = ws + 12599808;
    float* de     = ws + 12603904;
    float* dpsum  = ws + 12612096;
    float* dpctx  = ws + 12612224;
    float* y      = ws + 16777216;
    float* hb     = ws + 20971520;
    float* cb     = ws + 20975616;
    float* inp    = ws + 20979712;
    float* pk0f   = ws + 21176320;
    float* pk0b   = ws + 21438464;
    float* pk1f   = ws + 21700608;
    float* pk1b   = ws + 21962752;
    float* pdWih0 = ws + 22224896;
    float* pdWhh0 = ws + 22511616;
    float* pdWih1 = ws + 22773760;
    float* pdWhh1 = ws + 23035904;
    float* pWo1T  = ws + 23298048;
    float* pWaT   = ws + 23363584;

    // packing
    k_inp<<<768, 256, 0, stream>>>(x, u, inp);
    k_pack4<<<1024, 256, 0, stream>>>(eWhh_f0, pk0f, 256);
    k_pack4<<<1024, 256, 0, stream>>>(eWhh_b0, pk0b, 256);
    k_pack4<<<1024, 256, 0, stream>>>(eWhh_f1, pk1f, 256);
    k_pack4<<<1024, 256, 0, stream>>>(eWhh_b1, pk1b, 256);
    k_pack4<<<1120, 256, 0, stream>>>(dWih0, pdWih0, 280);
    k_pack4<<<1024, 256, 0, stream>>>(dWhh0, pdWhh0, 256);
    k_pack4<<<1024, 256, 0, stream>>>(dWih1, pdWih1, 256);
    k_pack4<<<1024, 256, 0, stream>>>(dWhh1, pdWhh1, 256);
    k_trT<<<256, 256, 0, stream>>>(Wa, 512, pWaT);
    k_trT<<<256, 256, 0, stream>>>(Wo1, 256, pWo1T);

    // encoder
    k_ngemm<<<32768, 256, 0, stream>>>(inp, 24, eWih_f0, 24, ebih_f0, ebhh_f0, A, 8192, 1024, 24);
    k_ngemm<<<32768, 256, 0, stream>>>(inp, 24, eWih_b0, 24, ebih_b0, ebhh_b0, A + 8388608, 8192, 1024, 24);
    k_recR<<<dim3(16, 2), 1024, 0, stream>>>(A, pk0f, pk0b, y, nullptr, nullptr);
    k_gemm<<<dim3(128, 16), 256, 0, stream>>>(y, 512, eWih_f1, 512, 0, ebih_f1, ebhh_f1, A, 1024, 512);
    k_gemm<<<dim3(128, 16), 256, 0, stream>>>(y, 512, eWih_b1, 512, 0, ebih_b1, ebhh_b1, A + 8388608, 1024, 512);
    k_recR<<<dim3(16, 2), 1024, 0, stream>>>(A, pk1f, pk1b, y, hb, cb);
    k_gemm<<<dim3(128, 4), 256, 0, stream>>>(y, 512, Wp, 512, 0, bp, nullptr, enc, 256, 512);
    k_gemm<<<dim3(128, 4), 256, 0, stream>>>(enc, 256, Wa, 512, 256, ba, nullptr, EpTmp, 256, 256);
    k_trEp<<<8192, 256, 0, stream>>>(EpTmp, Ept);

    // decoder
    d_init<<<16, 256, 0, stream>>>(x, u, hb, cb, pWaT, dh0, dc0, dh1, dc1, ddin, dqW);
    for (int t = 0; t < T_LEN; t++) {
        d_attn<<<dim3(16, 8), 256, 0, stream>>>(Ept, enc, dqW, va, de, dpsum, dpctx);
        d_step<<<16, 1024, 0, stream>>>(de, dpsum, dpctx, ddin, dh0, dc0, dh1, dc1, dqW,
                                        pdWih0, pdWhh0, dbih0, dbhh0,
                                        pdWih1, pdWhh1, dbih1, dbhh1,
                                        pWo1T, bo1, Wo2, bo2, pWaT, t, (float*)d_out);
    }
}

// Round 11
// 7527.319 us; speedup vs baseline: 3.0950x; 3.0950x over previous
//
#include <hip/hip_runtime.h>
#include <hip/hip_bf16.h>

// LSTMSeq2SeqModel: B=16, S=512, T=48, H=256, X=16, U=8. Output f32 (proven r6).
// Round 11: revert r10's spilled register-resident recurrence (VGPR_Count=64
// proved scratch demotion). Back to r8's proven structure; the per-CU L2 port
// bound (1MB Whh/step @ ~141 GB/s = 7.4us/step) is attacked by HALVING BYTES:
// Whh and the 4 decoder cell matrices stored fp16, dots via v_dot2_f32_f16
// (2 fp16 MACs/instr, f32 accumulate); h/din mirrored fp16 in LDS. All state
// (c, h, y, ctx, softmax, projections) stays fp32.
//
// ws layout (floats) as r8; pk/pdW slots reinterpreted as fp16 (half size):
//   A/Gx @ 0 [2][8192][1024]; after rec1: enc@0, EpTmp@2097152, Ept@4194304
//   dh0@12582912 dc0@12587008 dh1@12591104 dc1@12595200 ddin@12599296
//   dqW@12599808 de@12603904 dpsum@12612096 dpctx@12612224
//   y@16777216 hb@20971520 cb@20975616 inp@20979712
//   phk0f@21176320 phk0b@21438464 phk1f@21700608 phk1b@21962752 (ushort)
//   pdWih0h@22224896 pdWhh0h@22511616 pdWih1h@22773760 pdWhh1h@23035904 (ushort)
//   pWo1T@23298048 pWaT@23363584 (f32)

#define S_LEN 512
#define BATCH 16
#define T_LEN 48
#define WS_NEED_BYTES 93716480ull

__device__ __forceinline__ float sigm(float x) { return 1.f / (1.f + expf(-x)); }

typedef _Float16 h2v __attribute__((ext_vector_type(2)));

__device__ __forceinline__ float dot2u(unsigned int a, unsigned int b, float c)
{
    union U { unsigned int u; h2v h; };
    U ua; ua.u = a; U ub; ub.u = b;
#if __has_builtin(__builtin_amdgcn_fdot2)
    return __builtin_amdgcn_fdot2(ua.h, ub.h, c, false);
#else
    return c + (float)ua.h[0] * (float)ub.h[0] + (float)ua.h[1] * (float)ub.h[1];
#endif
}

__device__ __forceinline__ unsigned short f2h(float f)
{
    _Float16 h = (_Float16)f;
    union { _Float16 h; unsigned short u; } v; v.h = h;
    return v.u;
}

__global__ __launch_bounds__(256) void k_guard(float* __restrict__ outp,
                                               int out_size, float v)
{
    int idx = blockIdx.x * 256 + threadIdx.x;
    if (idx >= out_size) return;
    outp[idx] = (idx < 6144) ? v : 0.f;
}

__global__ __launch_bounds__(256) void k_inp(const float* __restrict__ x,
                                             const float* __restrict__ u,
                                             float* __restrict__ inp)
{
    int idx = blockIdx.x * 256 + threadIdx.x;
    if (idx >= 8192 * 24) return;
    int m = idx / 24, c = idx - m * 24;
    int t = m >> 4, b = m & 15;
    inp[idx] = (c < 16) ? x[((size_t)b * S_LEN + t) * 16 + c]
                        : u[((size_t)b * S_LEN + t) * 8 + (c - 16)];
}

// pack W[1024][K] -> fp16 layout [K/8][1024][8]
__global__ __launch_bounds__(256) void k_packh(const float* __restrict__ W,
                                               unsigned short* __restrict__ dst, int K)
{
    int idx = blockIdx.x * 256 + threadIdx.x;
    if (idx >= 1024 * K) return;
    int g = idx / K, k = idx - g * K;
    dst[(((k >> 3) * 1024 + g) << 3) + (k & 7)] = f2h(W[idx]);
}

__global__ __launch_bounds__(256) void k_trT(const float* __restrict__ W, int ld,
                                             float* __restrict__ dst)
{
    int idx = blockIdx.x * 256 + threadIdx.x;   // 65536
    int n = idx >> 8, k = idx & 255;
    dst[k * 256 + n] = W[(size_t)n * ld + k];
}

__global__ __launch_bounds__(256) void k_trEp(const float* __restrict__ src,
                                              float* __restrict__ dst)
{
    int idx = blockIdx.x * 256 + threadIdx.x;   // 2097152
    int m = idx >> 8, k = idx & 255;
    int s = m >> 4, b = m & 15;
    dst[((size_t)(b * 256 + k) << 9) + s] = src[idx];
}

__global__ __launch_bounds__(256) void k_ngemm(
    const float* __restrict__ A, int lda,
    const float* __restrict__ B, int ldb,
    const float* __restrict__ bias1, const float* __restrict__ bias2,
    float* __restrict__ C, int M, int N, int K)
{
    int id = blockIdx.x * 256 + threadIdx.x;
    if (id >= M * N) return;
    int m = id / N, n = id - m * N;
    const float* a  = A + (size_t)m * lda;
    const float* br = B + (size_t)n * ldb;
    float s = bias1[n] + bias2[n];
#pragma unroll 8
    for (int k = 0; k < K; k++) s += a[k] * br[k];
    C[id] = s;
}

#define BM 64
#define BN 64
#define BK 16
__global__ __launch_bounds__(256) void k_gemm(
    const float* __restrict__ A, int lda,
    const float* __restrict__ B, int ldb, int bco,
    const float* __restrict__ bias1, const float* __restrict__ bias2,
    float* __restrict__ C, int N, int K)
{
    __shared__ float As[BK][BM + 4];
    __shared__ float Bs[BK][BN + 4];
    int tid = threadIdx.x;
    int m0 = blockIdx.x * BM, n0 = blockIdx.y * BN;
    int tx = tid & 15, ty = tid >> 4;
    float acc[4][4] = {};
    int lr = tid >> 2;
    int lk4 = (tid & 3) * 4;
    for (int k0 = 0; k0 < K; k0 += BK) {
        float4 av = *(const float4*)(A + (size_t)(m0 + lr) * lda + k0 + lk4);
        float4 bv = *(const float4*)(B + (size_t)(n0 + lr) * ldb + bco + k0 + lk4);
        As[lk4 + 0][lr] = av.x; As[lk4 + 1][lr] = av.y; As[lk4 + 2][lr] = av.z; As[lk4 + 3][lr] = av.w;
        Bs[lk4 + 0][lr] = bv.x; Bs[lk4 + 1][lr] = bv.y; Bs[lk4 + 2][lr] = bv.z; Bs[lk4 + 3][lr] = bv.w;
        __syncthreads();
#pragma unroll
        for (int k = 0; k < BK; k++) {
            const float4 a  = *(const float4*)&As[k][ty * 4];
            const float4 bq = *(const float4*)&Bs[k][tx * 4];
            acc[0][0] += a.x * bq.x; acc[0][1] += a.x * bq.y; acc[0][2] += a.x * bq.z; acc[0][3] += a.x * bq.w;
            acc[1][0] += a.y * bq.x; acc[1][1] += a.y * bq.y; acc[1][2] += a.y * bq.z; acc[1][3] += a.y * bq.w;
            acc[2][0] += a.z * bq.x; acc[2][1] += a.z * bq.y; acc[2][2] += a.z * bq.z; acc[2][3] += a.z * bq.w;
            acc[3][0] += a.w * bq.x; acc[3][1] += a.w * bq.y; acc[3][2] += a.w * bq.z; acc[3][3] += a.w * bq.w;
        }
        __syncthreads();
    }
    float bs[4];
#pragma unroll
    for (int jj = 0; jj < 4; jj++) {
        int n = n0 + tx * 4 + jj;
        bs[jj] = bias1[n] + (bias2 ? bias2[n] : 0.f);
    }
#pragma unroll
    for (int ii = 0; ii < 4; ii++) {
        float4 o = make_float4(acc[ii][0] + bs[0], acc[ii][1] + bs[1],
                               acc[ii][2] + bs[2], acc[ii][3] + bs[3]);
        *(float4*)(C + (size_t)(m0 + ty * 4 + ii) * N + n0 + tx * 4) = o;
    }
}

// ---------------- recurrence, fp16 weights + dot2: grid(16,2) x 1024, thread=gate.
__global__ __launch_bounds__(1024) void k_recH(
    const float* __restrict__ Gx,
    const unsigned short* __restrict__ phF, const unsigned short* __restrict__ phB,
    float* __restrict__ y,
    float* __restrict__ hbO, float* __restrict__ cbO)
{
    int b = blockIdx.x, dir = blockIdx.y, tid = threadIdx.x;
    const uint4* pk = (const uint4*)(dir ? phB : phF);   // [32][1024] x 16B (8 halves)
    const float* gx = Gx + (size_t)dir * 8388608;
    __shared__ __align__(16) unsigned short hsh[256];    // h in fp16
    __shared__ float gsh[1024];
    if (tid < 256) hsh[tid] = 0;                         // fp16 zero
    float c = 0.f, hn = 0.f;
    __syncthreads();
    for (int step = 0; step < S_LEN; step++) {
        int t = dir ? (S_LEN - 1 - step) : step;
        float s = gx[((size_t)t * BATCH + b) * 1024 + tid];
        const uint4* h16 = (const uint4*)hsh;            // 32 chunks, broadcast reads
#pragma unroll 8
        for (int k8 = 0; k8 < 32; k8++) {
            uint4 w = pk[k8 * 1024 + tid];
            uint4 hv = h16[k8];
            s = dot2u(w.x, hv.x, s);
            s = dot2u(w.y, hv.y, s);
            s = dot2u(w.z, hv.z, s);
            s = dot2u(w.w, hv.w, s);
        }
        gsh[tid] = s;
        __syncthreads();
        if (tid < 256) {
            float i = sigm(gsh[tid]), f = sigm(gsh[256 + tid]);
            float gg = tanhf(gsh[512 + tid]), o = sigm(gsh[768 + tid]);
            c = f * c + i * gg;
            hn = o * tanhf(c);
            hsh[tid] = f2h(hn);
            y[((size_t)t * BATCH + b) * 512 + dir * 256 + tid] = hn;
        }
        __syncthreads();
    }
    if (hbO && dir == 1 && tid < 256) { hbO[b * 256 + tid] = hn; cbO[b * 256 + tid] = c; }
}

// ---------------- decoder prologue: state init + qW0. grid 16 x 256.
__global__ __launch_bounds__(256) void d_init(
    const float* __restrict__ x, const float* __restrict__ u,
    const float* __restrict__ hb, const float* __restrict__ cb,
    const float* __restrict__ pWaT,
    float* __restrict__ dh0, float* __restrict__ dc0,
    float* __restrict__ dh1, float* __restrict__ dc1,
    float* __restrict__ ddin, float* __restrict__ dqW)
{
    int b = blockIdx.x, tid = threadIdx.x;
    __shared__ float h1s[256];
    float hv = hb[b * 256 + tid], cv = cb[b * 256 + tid];
    dh0[b * 256 + tid] = hv; dh1[b * 256 + tid] = hv;
    dc0[b * 256 + tid] = cv; dc1[b * 256 + tid] = cv;
    h1s[tid] = hv;
    if (tid < 16) ddin[b * 24 + tid] = x[((size_t)b * S_LEN + (S_LEN - 1)) * 16 + tid];
    else if (tid < 24) ddin[b * 24 + tid] = u[((size_t)b * S_LEN + (S_LEN - 1)) * 8 + (tid - 16)];
    __syncthreads();
    float s = 0.f;
    for (int k = 0; k < 256; k++) s += h1s[k] * pWaT[k * 256 + tid];
    dqW[b * 256 + tid] = s;
}

// ---------------- attention scan: grid (16,8) x 256.
__global__ __launch_bounds__(256) void d_attn(
    const float* __restrict__ Ept, const float* __restrict__ enc,
    const float* __restrict__ dqW, const float* __restrict__ va,
    float* __restrict__ de, float* __restrict__ dpsum, float* __restrict__ dpctx)
{
    int b = blockIdx.x, sc = blockIdx.y, tid = threadIdx.x;
    int sl = tid & 63, q = tid >> 6;
    __shared__ float qWs[256], vsh[256], red[256], esh[64];
    qWs[tid] = dqW[b * 256 + tid];
    vsh[tid] = va[tid];
    __syncthreads();
    const float* ep = Ept + (((size_t)(b * 256 + q * 64)) << 9) + sc * 64 + sl;
    float part = 0.f;
#pragma unroll 8
    for (int m = 0; m < 64; m++)
        part += tanhf(ep[(size_t)m << 9] + qWs[q * 64 + m]) * vsh[q * 64 + m];
    red[tid] = part;
    __syncthreads();
    if (q == 0) {
        float a = red[sl] + red[64 + sl] + red[128 + sl] + red[192 + sl];
        float e = expf(a);               // no max-sub: |alpha| <= sum|va| ~ 10
        esh[sl] = e;
        de[b * 512 + sc * 64 + sl] = e;
    }
    __syncthreads();
    if (tid == 0) {
        float s = 0.f;
        for (int i = 0; i < 64; i++) s += esh[i];
        dpsum[b * 8 + sc] = s;
    }
    float cp = 0.f;
#pragma unroll 4
    for (int s1 = 0; s1 < 64; s1++)
        cp += esh[s1] * enc[((size_t)((sc * 64 + s1) * BATCH + b) << 8) + tid];
    dpctx[((b * 8 + sc) << 8) + tid] = cp;
}

// ---------------- sequential core: grid 16 x 1024, fp16 cell weights.
__global__ __launch_bounds__(1024) void d_step(
    const float* __restrict__ de, const float* __restrict__ dpsum,
    const float* __restrict__ dpctx,
    float* __restrict__ ddin, float* __restrict__ dh0, float* __restrict__ dc0,
    float* __restrict__ dh1, float* __restrict__ dc1, float* __restrict__ dqW,
    const unsigned short* __restrict__ pdWih0h, const unsigned short* __restrict__ pdWhh0h,
    const float* __restrict__ dbih0, const float* __restrict__ dbhh0,
    const unsigned short* __restrict__ pdWih1h, const unsigned short* __restrict__ pdWhh1h,
    const float* __restrict__ dbih1, const float* __restrict__ dbhh1,
    const float* __restrict__ pWo1T, const float* __restrict__ bo1,
    const float* __restrict__ Wo2, const float* __restrict__ bo2,
    const float* __restrict__ pWaT, int t, float* __restrict__ outp)
{
    int b = blockIdx.x, tid = threadIdx.x;
    __shared__ __align__(16) unsigned short dinh[280], h0h[256], h1h[256];
    __shared__ float h1s[256];
    __shared__ float comb[1024], r1[256];
    __shared__ float Sig;
    float c0r = 0.f, c1r = 0.f;
    if (tid < 256) {
        float h0v = dh0[b * 256 + tid], h1v = dh1[b * 256 + tid];
        h0h[tid] = f2h(h0v); h1h[tid] = f2h(h1v); h1s[tid] = h1v;
        c0r = dc0[b * 256 + tid]; c1r = dc1[b * 256 + tid];
    }
    if (tid < 24) dinh[tid] = f2h(ddin[b * 24 + tid]);
    if (tid == 0) {
        float s = 0.f;
        const float* ps = dpsum + b * 8;
        for (int i = 0; i < 8; i++) s += ps[i];
        Sig = s;
    }
    __syncthreads();
    float inv = 1.f / Sig;
    if (tid < 512)
        outp[6144 + ((size_t)(b * T_LEN + t)) * 512 + tid] = de[b * 512 + tid] * inv;
    if (tid < 256) {
        float s = 0.f;
        for (int sc = 0; sc < 8; sc++) s += dpctx[((b * 8 + sc) << 8) + tid];
        dinh[24 + tid] = f2h(s * inv);
    }
    __syncthreads();
    // cell0: input = dinh[280] (35 chunks), hidden = h0h (32 chunks)
    {
        const uint4* wi = (const uint4*)pdWih0h;
        const uint4* wh = (const uint4*)pdWhh0h;
        const uint4* d16 = (const uint4*)dinh;
        const uint4* h16 = (const uint4*)h0h;
        float s = dbih0[tid] + dbhh0[tid];
#pragma unroll 5
        for (int k8 = 0; k8 < 35; k8++) {
            uint4 w = wi[k8 * 1024 + tid]; uint4 v = d16[k8];
            s = dot2u(w.x, v.x, s); s = dot2u(w.y, v.y, s);
            s = dot2u(w.z, v.z, s); s = dot2u(w.w, v.w, s);
        }
#pragma unroll 8
        for (int k8 = 0; k8 < 32; k8++) {
            uint4 w = wh[k8 * 1024 + tid]; uint4 v = h16[k8];
            s = dot2u(w.x, v.x, s); s = dot2u(w.y, v.y, s);
            s = dot2u(w.z, v.z, s); s = dot2u(w.w, v.w, s);
        }
        comb[tid] = s;
    }
    __syncthreads();
    if (tid < 256) {
        float i = sigm(comb[tid]), f = sigm(comb[256 + tid]);
        float gg = tanhf(comb[512 + tid]), o = sigm(comb[768 + tid]);
        float c = f * c0r + i * gg;
        dc0[b * 256 + tid] = c;
        float hn = o * tanhf(c);
        h0h[tid] = f2h(hn); dh0[b * 256 + tid] = hn;
    }
    __syncthreads();
    // cell1: input = new h0h, hidden = h1h
    {
        const uint4* wi = (const uint4*)pdWih1h;
        const uint4* wh = (const uint4*)pdWhh1h;
        const uint4* a16 = (const uint4*)h0h;
        const uint4* h16 = (const uint4*)h1h;
        float s = dbih1[tid] + dbhh1[tid];
#pragma unroll 8
        for (int k8 = 0; k8 < 32; k8++) {
            uint4 w = wi[k8 * 1024 + tid]; uint4 v = a16[k8];
            s = dot2u(w.x, v.x, s); s = dot2u(w.y, v.y, s);
            s = dot2u(w.z, v.z, s); s = dot2u(w.w, v.w, s);
        }
#pragma unroll 8
        for (int k8 = 0; k8 < 32; k8++) {
            uint4 w = wh[k8 * 1024 + tid]; uint4 v = h16[k8];
            s = dot2u(w.x, v.x, s); s = dot2u(w.y, v.y, s);
            s = dot2u(w.z, v.z, s); s = dot2u(w.w, v.w, s);
        }
        comb[tid] = s;
    }
    __syncthreads();
    if (tid < 256) {
        float i = sigm(comb[tid]), f = sigm(comb[256 + tid]);
        float gg = tanhf(comb[512 + tid]), o = sigm(comb[768 + tid]);
        float c = f * c1r + i * gg;
        dc1[b * 256 + tid] = c;
        float hn = o * tanhf(c);
        h1s[tid] = hn; h1h[tid] = f2h(hn); dh1[b * 256 + tid] = hn;
    }
    __syncthreads();
    // out projection (fp32)
    {
        int o = tid & 255, q = tid >> 8;
        float s = 0.f;
        for (int k = q * 64; k < q * 64 + 64; k++) s += h1s[k] * pWo1T[k * 256 + o];
        comb[tid] = s;
    }
    __syncthreads();
    if (tid < 256) r1[tid] = fmaxf(bo1[tid] + comb[tid] + comb[256 + tid] + comb[512 + tid] + comb[768 + tid], 0.f);
    __syncthreads();
    if (tid < 256) {
        int o = tid >> 5, l = tid & 31;
        const float* wr = Wo2 + (size_t)o * 256;
        float s = 0.f;
#pragma unroll
        for (int m = 0; m < 8; m++) { int k = l + m * 32; s += r1[k] * wr[k]; }
        comb[tid] = s;
    }
    __syncthreads();
    if (tid < 8) {
        float s = bo2[tid];
        for (int l = 0; l < 32; l++) s += comb[tid * 32 + l];
        outp[((size_t)(b * T_LEN + t)) * 8 + tid] = s;
        ddin[b * 24 + 16 + tid] = s;
    }
    __syncthreads();
    // next-step qW (fp32)
    {
        int n = tid & 255, q = tid >> 8;
        float s = 0.f;
        for (int k = q * 64; k < q * 64 + 64; k++) s += h1s[k] * pWaT[k * 256 + n];
        comb[tid] = s;
    }
    __syncthreads();
    if (tid < 256) dqW[b * 256 + tid] = comb[tid] + comb[256 + tid] + comb[512 + tid] + comb[768 + tid];
}

extern "C" void kernel_launch(void* const* d_in, const int* in_sizes, int n_in,
                              void* d_out, int out_size, void* d_ws, size_t ws_size,
                              hipStream_t stream) {
    static const int kExp[36] = {
        131072, 65536, 1,
        24576, 262144, 1024, 1024,
        24576, 262144, 1024, 1024,
        524288, 262144, 1024, 1024,
        524288, 262144, 1024, 1024,
        131072, 256,
        286720, 262144, 1024, 1024,
        262144, 262144, 1024, 1024,
        131072, 256, 256,
        65536, 256, 2048, 8
    };
    bool ok = (n_in == 36);
    if (ok) for (int i = 0; i < 36; i++) if (in_sizes[i] != kExp[i]) { ok = false; break; }
    if (!ok) { k_guard<<<(out_size + 255) / 256, 256, 0, stream>>>((float*)d_out, out_size, 0.05f); return; }
    if (out_size != 399360) { k_guard<<<(out_size + 255) / 256, 256, 0, stream>>>((float*)d_out, out_size, 0.07f); return; }
    if (ws_size < WS_NEED_BYTES) {
        float v = (float)(ws_size >> 20) * 1e-4f;
        k_guard<<<(out_size + 255) / 256, 256, 0, stream>>>((float*)d_out, out_size, v);
        return;
    }

    const float* x       = (const float*)d_in[0];
    const float* u       = (const float*)d_in[1];
    const float* eWih_f0 = (const float*)d_in[3];
    const float* eWhh_f0 = (const float*)d_in[4];
    const float* ebih_f0 = (const float*)d_in[5];
    const float* ebhh_f0 = (const float*)d_in[6];
    const float* eWih_b0 = (const float*)d_in[7];
    const float* eWhh_b0 = (const float*)d_in[8];
    const float* ebih_b0 = (const float*)d_in[9];
    const float* ebhh_b0 = (const float*)d_in[10];
    const float* eWih_f1 = (const float*)d_in[11];
    const float* eWhh_f1 = (const float*)d_in[12];
    const float* ebih_f1 = (const float*)d_in[13];
    const float* ebhh_f1 = (const float*)d_in[14];
    const float* eWih_b1 = (const float*)d_in[15];
    const float* eWhh_b1 = (const float*)d_in[16];
    const float* ebih_b1 = (const float*)d_in[17];
    const float* ebhh_b1 = (const float*)d_in[18];
    const float* Wp      = (const float*)d_in[19];
    const float* bp      = (const float*)d_in[20];
    const float* dWih0   = (const float*)d_in[21];
    const float* dWhh0   = (const float*)d_in[22];
    const float* dbih0   = (const float*)d_in[23];
    const float* dbhh0   = (const float*)d_in[24];
    const float* dWih1   = (const float*)d_in[25];
    const float* dWhh1   = (const float*)d_in[26];
    const float* dbih1   = (const float*)d_in[27];
    const float* dbhh1   = (const float*)d_in[28];
    const float* Wa      = (const float*)d_in[29];
    const float* ba      = (const float*)d_in[30];
    const float* va      = (const float*)d_in[31];
    const float* Wo1     = (const float*)d_in[32];
    const float* bo1     = (const float*)d_in[33];
    const float* Wo2     = (const float*)d_in[34];
    const float* bo2     = (const float*)d_in[35];

    float* ws = (float*)d_ws;
    float* A      = ws;
    float* enc    = ws;
    float* EpTmp  = ws + 2097152;
    float* Ept    = ws + 4194304;
    float* dh0    = ws + 12582912;
    float* dc0    = ws + 12587008;
    float* dh1    = ws + 12591104;
    float* dc1    = ws + 12595200;
    float* ddin   = ws + 12599296;
    float* dqW    = ws + 12599808;
    float* de     = ws + 12603904;
    float* dpsum  = ws + 12612096;
    float* dpctx  = ws + 12612224;
    float* y      = ws + 16777216;
    float* hb     = ws + 20971520;
    float* cb     = ws + 20975616;
    float* inp    = ws + 20979712;
    unsigned short* phk0f   = (unsigned short*)(ws + 21176320);
    unsigned short* phk0b   = (unsigned short*)(ws + 21438464);
    unsigned short* phk1f   = (unsigned short*)(ws + 21700608);
    unsigned short* phk1b   = (unsigned short*)(ws + 21962752);
    unsigned short* pdWih0h = (unsigned short*)(ws + 22224896);
    unsigned short* pdWhh0h = (unsigned short*)(ws + 22511616);
    unsigned short* pdWih1h = (unsigned short*)(ws + 22773760);
    unsigned short* pdWhh1h = (unsigned short*)(ws + 23035904);
    float* pWo1T  = ws + 23298048;
    float* pWaT   = ws + 23363584;

    // packing
    k_inp<<<768, 256, 0, stream>>>(x, u, inp);
    k_packh<<<1024, 256, 0, stream>>>(eWhh_f0, phk0f, 256);
    k_packh<<<1024, 256, 0, stream>>>(eWhh_b0, phk0b, 256);
    k_packh<<<1024, 256, 0, stream>>>(eWhh_f1, phk1f, 256);
    k_packh<<<1024, 256, 0, stream>>>(eWhh_b1, phk1b, 256);
    k_packh<<<1120, 256, 0, stream>>>(dWih0, pdWih0h, 280);
    k_packh<<<1024, 256, 0, stream>>>(dWhh0, pdWhh0h, 256);
    k_packh<<<1024, 256, 0, stream>>>(dWih1, pdWih1h, 256);
    k_packh<<<1024, 256, 0, stream>>>(dWhh1, pdWhh1h, 256);
    k_trT<<<256, 256, 0, stream>>>(Wa, 512, pWaT);
    k_trT<<<256, 256, 0, stream>>>(Wo1, 256, pWo1T);

    // encoder
    k_ngemm<<<32768, 256, 0, stream>>>(inp, 24, eWih_f0, 24, ebih_f0, ebhh_f0, A, 8192, 1024, 24);
    k_ngemm<<<32768, 256, 0, stream>>>(inp, 24, eWih_b0, 24, ebih_b0, ebhh_b0, A + 8388608, 8192, 1024, 24);
    k_recH<<<dim3(16, 2), 1024, 0, stream>>>(A, phk0f, phk0b, y, nullptr, nullptr);
    k_gemm<<<dim3(128, 16), 256, 0, stream>>>(y, 512, eWih_f1, 512, 0, ebih_f1, ebhh_f1, A, 1024, 512);
    k_gemm<<<dim3(128, 16), 256, 0, stream>>>(y, 512, eWih_b1, 512, 0, ebih_b1, ebhh_b1, A + 8388608, 1024, 512);
    k_recH<<<dim3(16, 2), 1024, 0, stream>>>(A, phk1f, phk1b, y, hb, cb);
    k_gemm<<<dim3(128, 4), 256, 0, stream>>>(y, 512, Wp, 512, 0, bp, nullptr, enc, 256, 512);
    k_gemm<<<dim3(128, 4), 256, 0, stream>>>(enc, 256, Wa, 512, 256, ba, nullptr, EpTmp, 256, 256);
    k_trEp<<<8192, 256, 0, stream>>>(EpTmp, Ept);

    // decoder
    d_init<<<16, 256, 0, stream>>>(x, u, hb, cb, pWaT, dh0, dc0, dh1, dc1, ddin, dqW);
    for (int t = 0; t < T_LEN; t++) {
        d_attn<<<dim3(16, 8), 256, 0, stream>>>(Ept, enc, dqW, va, de, dpsum, dpctx);
        d_step<<<16, 1024, 0, stream>>>(de, dpsum, dpctx, ddin, dh0, dc0, dh1, dc1, dqW,
                                        pdWih0h, pdWhh0h, dbih0, dbhh0,
                                        pdWih1h, pdWhh1h, dbih1, dbhh1,
                                        pWo1T, bo1, Wo2, bo2, pWaT, t, (float*)d_out);
    }
}

// Round 12
// 6723.324 us; speedup vs baseline: 3.4651x; 1.1196x over previous
//
#include <hip/hip_runtime.h>
#include <hip/hip_bf16.h>

// LSTMSeq2SeqModel: B=16, S=512, T=48, H=256, X=16, U=8. Output f32 (proven r6).
// Round 12: k_recH -> k_recL: first 64 k-cols of fp16 Whh LDS-resident (128 KB,
// loaded once), remaining 192 cols streamed (384 KB/step vs 512) -> per-step
// 4.28 -> ~3.2us. d_step projections (Wo1T, WaT) pair-packed fp16 via dot2.
// No cross-block sync anywhere (r9/r10 lessons).
//
// ws layout (floats) as r11; fp16 packs reuse r8 slots; new fp16 proj packs
// live in the free halves of the phk slots:
//   A/Gx @ 0 [2][8192][1024]; after rec1: enc@0, EpTmp@2097152, Ept@4194304
//   dh0@12582912 dc0@12587008 dh1@12591104 dc1@12595200 ddin@12599296
//   dqW@12599808 de@12603904 dpsum@12612096 dpctx@12612224
//   y@16777216 hb@20971520 cb@20975616 inp@20979712
//   phk0f@21176320(131072f) pWo1Th@21307392(32768f)
//   phk0b@21438464(131072f) pWaTh@21569536(32768f)
//   phk1f@21700608 phk1b@21962752
//   pdWih0h@22224896 pdWhh0h@22511616 pdWih1h@22773760 pdWhh1h@23035904
//   pWaT@23363584 (f32, d_init only)

#define S_LEN 512
#define BATCH 16
#define T_LEN 48
#define WS_NEED_BYTES 93716480ull

__device__ __forceinline__ float sigm(float x) { return 1.f / (1.f + expf(-x)); }

typedef _Float16 h2v __attribute__((ext_vector_type(2)));

__device__ __forceinline__ float dot2u(unsigned int a, unsigned int b, float c)
{
    union U { unsigned int u; h2v h; };
    U ua; ua.u = a; U ub; ub.u = b;
#if __has_builtin(__builtin_amdgcn_fdot2)
    return __builtin_amdgcn_fdot2(ua.h, ub.h, c, false);
#else
    return c + (float)ua.h[0] * (float)ub.h[0] + (float)ua.h[1] * (float)ub.h[1];
#endif
}

__device__ __forceinline__ unsigned short f2h(float f)
{
    _Float16 h = (_Float16)f;
    union { _Float16 h; unsigned short u; } v; v.h = h;
    return v.u;
}

__global__ __launch_bounds__(256) void k_guard(float* __restrict__ outp,
                                               int out_size, float v)
{
    int idx = blockIdx.x * 256 + threadIdx.x;
    if (idx >= out_size) return;
    outp[idx] = (idx < 6144) ? v : 0.f;
}

__global__ __launch_bounds__(256) void k_inp(const float* __restrict__ x,
                                             const float* __restrict__ u,
                                             float* __restrict__ inp)
{
    int idx = blockIdx.x * 256 + threadIdx.x;
    if (idx >= 8192 * 24) return;
    int m = idx / 24, c = idx - m * 24;
    int t = m >> 4, b = m & 15;
    inp[idx] = (c < 16) ? x[((size_t)b * S_LEN + t) * 16 + c]
                        : u[((size_t)b * S_LEN + t) * 8 + (c - 16)];
}

// pack W[1024][K] -> fp16 layout [K/8][1024][8]
__global__ __launch_bounds__(256) void k_packh(const float* __restrict__ W,
                                               unsigned short* __restrict__ dst, int K)
{
    int idx = blockIdx.x * 256 + threadIdx.x;
    if (idx >= 1024 * K) return;
    int g = idx / K, k = idx - g * K;
    dst[(((k >> 3) * 1024 + g) << 3) + (k & 7)] = f2h(W[idx]);
}

// f32 W[256 rows][ld], first 256 cols -> fp16 pair layout dst[k/2][256][2]
__global__ __launch_bounds__(256) void k_trTh(const float* __restrict__ W, int ld,
                                              unsigned short* __restrict__ dst)
{
    int idx = blockIdx.x * 256 + threadIdx.x;   // 65536
    int n = idx >> 8, k = idx & 255;
    dst[(((k >> 1) * 256 + n) << 1) + (k & 1)] = f2h(W[(size_t)n * ld + k]);
}

__global__ __launch_bounds__(256) void k_trT(const float* __restrict__ W, int ld,
                                             float* __restrict__ dst)
{
    int idx = blockIdx.x * 256 + threadIdx.x;   // 65536
    int n = idx >> 8, k = idx & 255;
    dst[k * 256 + n] = W[(size_t)n * ld + k];
}

__global__ __launch_bounds__(256) void k_trEp(const float* __restrict__ src,
                                              float* __restrict__ dst)
{
    int idx = blockIdx.x * 256 + threadIdx.x;   // 2097152
    int m = idx >> 8, k = idx & 255;
    int s = m >> 4, b = m & 15;
    dst[((size_t)(b * 256 + k) << 9) + s] = src[idx];
}

__global__ __launch_bounds__(256) void k_ngemm(
    const float* __restrict__ A, int lda,
    const float* __restrict__ B, int ldb,
    const float* __restrict__ bias1, const float* __restrict__ bias2,
    float* __restrict__ C, int M, int N, int K)
{
    int id = blockIdx.x * 256 + threadIdx.x;
    if (id >= M * N) return;
    int m = id / N, n = id - m * N;
    const float* a  = A + (size_t)m * lda;
    const float* br = B + (size_t)n * ldb;
    float s = bias1[n] + bias2[n];
#pragma unroll 8
    for (int k = 0; k < K; k++) s += a[k] * br[k];
    C[id] = s;
}

#define BM 64
#define BN 64
#define BK 16
__global__ __launch_bounds__(256) void k_gemm(
    const float* __restrict__ A, int lda,
    const float* __restrict__ B, int ldb, int bco,
    const float* __restrict__ bias1, const float* __restrict__ bias2,
    float* __restrict__ C, int N, int K)
{
    __shared__ float As[BK][BM + 4];
    __shared__ float Bs[BK][BN + 4];
    int tid = threadIdx.x;
    int m0 = blockIdx.x * BM, n0 = blockIdx.y * BN;
    int tx = tid & 15, ty = tid >> 4;
    float acc[4][4] = {};
    int lr = tid >> 2;
    int lk4 = (tid & 3) * 4;
    for (int k0 = 0; k0 < K; k0 += BK) {
        float4 av = *(const float4*)(A + (size_t)(m0 + lr) * lda + k0 + lk4);
        float4 bv = *(const float4*)(B + (size_t)(n0 + lr) * ldb + bco + k0 + lk4);
        As[lk4 + 0][lr] = av.x; As[lk4 + 1][lr] = av.y; As[lk4 + 2][lr] = av.z; As[lk4 + 3][lr] = av.w;
        Bs[lk4 + 0][lr] = bv.x; Bs[lk4 + 1][lr] = bv.y; Bs[lk4 + 2][lr] = bv.z; Bs[lk4 + 3][lr] = bv.w;
        __syncthreads();
#pragma unroll
        for (int k = 0; k < BK; k++) {
            const float4 a  = *(const float4*)&As[k][ty * 4];
            const float4 bq = *(const float4*)&Bs[k][tx * 4];
            acc[0][0] += a.x * bq.x; acc[0][1] += a.x * bq.y; acc[0][2] += a.x * bq.z; acc[0][3] += a.x * bq.w;
            acc[1][0] += a.y * bq.x; acc[1][1] += a.y * bq.y; acc[1][2] += a.y * bq.z; acc[1][3] += a.y * bq.w;
            acc[2][0] += a.z * bq.x; acc[2][1] += a.z * bq.y; acc[2][2] += a.z * bq.z; acc[2][3] += a.z * bq.w;
            acc[3][0] += a.w * bq.x; acc[3][1] += a.w * bq.y; acc[3][2] += a.w * bq.z; acc[3][3] += a.w * bq.w;
        }
        __syncthreads();
    }
    float bs[4];
#pragma unroll
    for (int jj = 0; jj < 4; jj++) {
        int n = n0 + tx * 4 + jj;
        bs[jj] = bias1[n] + (bias2 ? bias2[n] : 0.f);
    }
#pragma unroll
    for (int ii = 0; ii < 4; ii++) {
        float4 o = make_float4(acc[ii][0] + bs[0], acc[ii][1] + bs[1],
                               acc[ii][2] + bs[2], acc[ii][3] + bs[3]);
        *(float4*)(C + (size_t)(m0 + ty * 4 + ii) * N + n0 + tx * 4) = o;
    }
}

// ---------------- recurrence, fp16 weights, 128KB LDS-resident k-cols 0..63,
// cols 64..255 streamed. grid(16,2) x 1024, thread=gate.
__global__ __launch_bounds__(1024) void k_recL(
    const float* __restrict__ Gx,
    const unsigned short* __restrict__ phF, const unsigned short* __restrict__ phB,
    float* __restrict__ y,
    float* __restrict__ hbO, float* __restrict__ cbO)
{
    int b = blockIdx.x, dir = blockIdx.y, tid = threadIdx.x;
    const uint4* pk = (const uint4*)(dir ? phB : phF);   // [32][1024] x 16B
    const float* gx = Gx + (size_t)dir * 8388608;
    __shared__ uint4 Wl[8 * 1024];                       // 128 KB: k8 = 0..7
    __shared__ __align__(16) unsigned short hsh[256];    // h in fp16
    __shared__ float gsh[1024];
#pragma unroll
    for (int k8 = 0; k8 < 8; k8++) Wl[k8 * 1024 + tid] = pk[k8 * 1024 + tid];
    if (tid < 256) hsh[tid] = 0;
    float c = 0.f, hn = 0.f;
    __syncthreads();
    for (int step = 0; step < S_LEN; step++) {
        int t = dir ? (S_LEN - 1 - step) : step;
        float s = gx[((size_t)t * BATCH + b) * 1024 + tid];
        const uint4* h16 = (const uint4*)hsh;            // 32 chunks, broadcast
#pragma unroll
        for (int k8 = 0; k8 < 8; k8++) {                 // LDS-resident cols
            uint4 w = Wl[k8 * 1024 + tid];
            uint4 hv = h16[k8];
            s = dot2u(w.x, hv.x, s); s = dot2u(w.y, hv.y, s);
            s = dot2u(w.z, hv.z, s); s = dot2u(w.w, hv.w, s);
        }
#pragma unroll 8
        for (int k8 = 8; k8 < 32; k8++) {                // streamed cols
            uint4 w = pk[k8 * 1024 + tid];
            uint4 hv = h16[k8];
            s = dot2u(w.x, hv.x, s); s = dot2u(w.y, hv.y, s);
            s = dot2u(w.z, hv.z, s); s = dot2u(w.w, hv.w, s);
        }
        gsh[tid] = s;
        __syncthreads();
        if (tid < 256) {
            float i = sigm(gsh[tid]), f = sigm(gsh[256 + tid]);
            float gg = tanhf(gsh[512 + tid]), o = sigm(gsh[768 + tid]);
            c = f * c + i * gg;
            hn = o * tanhf(c);
            hsh[tid] = f2h(hn);
            y[((size_t)t * BATCH + b) * 512 + dir * 256 + tid] = hn;
        }
        __syncthreads();
    }
    if (hbO && dir == 1 && tid < 256) { hbO[b * 256 + tid] = hn; cbO[b * 256 + tid] = c; }
}

// ---------------- decoder prologue: state init + qW0. grid 16 x 256.
__global__ __launch_bounds__(256) void d_init(
    const float* __restrict__ x, const float* __restrict__ u,
    const float* __restrict__ hb, const float* __restrict__ cb,
    const float* __restrict__ pWaT,
    float* __restrict__ dh0, float* __restrict__ dc0,
    float* __restrict__ dh1, float* __restrict__ dc1,
    float* __restrict__ ddin, float* __restrict__ dqW)
{
    int b = blockIdx.x, tid = threadIdx.x;
    __shared__ float h1s[256];
    float hv = hb[b * 256 + tid], cv = cb[b * 256 + tid];
    dh0[b * 256 + tid] = hv; dh1[b * 256 + tid] = hv;
    dc0[b * 256 + tid] = cv; dc1[b * 256 + tid] = cv;
    h1s[tid] = hv;
    if (tid < 16) ddin[b * 24 + tid] = x[((size_t)b * S_LEN + (S_LEN - 1)) * 16 + tid];
    else if (tid < 24) ddin[b * 24 + tid] = u[((size_t)b * S_LEN + (S_LEN - 1)) * 8 + (tid - 16)];
    __syncthreads();
    float s = 0.f;
    for (int k = 0; k < 256; k++) s += h1s[k] * pWaT[k * 256 + tid];
    dqW[b * 256 + tid] = s;
}

// ---------------- attention scan: grid (16,8) x 256.
__global__ __launch_bounds__(256) void d_attn(
    const float* __restrict__ Ept, const float* __restrict__ enc,
    const float* __restrict__ dqW, const float* __restrict__ va,
    float* __restrict__ de, float* __restrict__ dpsum, float* __restrict__ dpctx)
{
    int b = blockIdx.x, sc = blockIdx.y, tid = threadIdx.x;
    int sl = tid & 63, q = tid >> 6;
    __shared__ float qWs[256], vsh[256], red[256], esh[64];
    qWs[tid] = dqW[b * 256 + tid];
    vsh[tid] = va[tid];
    __syncthreads();
    const float* ep = Ept + (((size_t)(b * 256 + q * 64)) << 9) + sc * 64 + sl;
    float part = 0.f;
#pragma unroll 8
    for (int m = 0; m < 64; m++)
        part += tanhf(ep[(size_t)m << 9] + qWs[q * 64 + m]) * vsh[q * 64 + m];
    red[tid] = part;
    __syncthreads();
    if (q == 0) {
        float a = red[sl] + red[64 + sl] + red[128 + sl] + red[192 + sl];
        float e = expf(a);               // no max-sub: |alpha| <= sum|va| ~ 10
        esh[sl] = e;
        de[b * 512 + sc * 64 + sl] = e;
    }
    __syncthreads();
    if (tid == 0) {
        float s = 0.f;
        for (int i = 0; i < 64; i++) s += esh[i];
        dpsum[b * 8 + sc] = s;
    }
    float cp = 0.f;
#pragma unroll 4
    for (int s1 = 0; s1 < 64; s1++)
        cp += esh[s1] * enc[((size_t)((sc * 64 + s1) * BATCH + b) << 8) + tid];
    dpctx[((b * 8 + sc) << 8) + tid] = cp;
}

// ---------------- sequential core: grid 16 x 1024, fp16 weights throughout.
__global__ __launch_bounds__(1024) void d_step(
    const float* __restrict__ de, const float* __restrict__ dpsum,
    const float* __restrict__ dpctx,
    float* __restrict__ ddin, float* __restrict__ dh0, float* __restrict__ dc0,
    float* __restrict__ dh1, float* __restrict__ dc1, float* __restrict__ dqW,
    const unsigned short* __restrict__ pdWih0h, const unsigned short* __restrict__ pdWhh0h,
    const float* __restrict__ dbih0, const float* __restrict__ dbhh0,
    const unsigned short* __restrict__ pdWih1h, const unsigned short* __restrict__ pdWhh1h,
    const float* __restrict__ dbih1, const float* __restrict__ dbhh1,
    const unsigned short* __restrict__ pWo1Th, const float* __restrict__ bo1,
    const float* __restrict__ Wo2, const float* __restrict__ bo2,
    const unsigned short* __restrict__ pWaTh, int t, float* __restrict__ outp)
{
    int b = blockIdx.x, tid = threadIdx.x;
    __shared__ __align__(16) unsigned short dinh[280];
    __shared__ __align__(16) unsigned short h0h[256];
    __shared__ __align__(16) unsigned short h1h[256];
    __shared__ float comb[1024], r1[256];
    __shared__ float Sig;
    float c0r = 0.f, c1r = 0.f;
    if (tid < 256) {
        h0h[tid] = f2h(dh0[b * 256 + tid]); h1h[tid] = f2h(dh1[b * 256 + tid]);
        c0r = dc0[b * 256 + tid]; c1r = dc1[b * 256 + tid];
    }
    if (tid < 24) dinh[tid] = f2h(ddin[b * 24 + tid]);
    if (tid == 0) {
        float s = 0.f;
        const float* ps = dpsum + b * 8;
        for (int i = 0; i < 8; i++) s += ps[i];
        Sig = s;
    }
    __syncthreads();
    float inv = 1.f / Sig;
    if (tid < 512)
        outp[6144 + ((size_t)(b * T_LEN + t)) * 512 + tid] = de[b * 512 + tid] * inv;
    if (tid < 256) {
        float s = 0.f;
        for (int sc = 0; sc < 8; sc++) s += dpctx[((b * 8 + sc) << 8) + tid];
        dinh[24 + tid] = f2h(s * inv);
    }
    __syncthreads();
    // cell0
    {
        const uint4* wi = (const uint4*)pdWih0h;
        const uint4* wh = (const uint4*)pdWhh0h;
        const uint4* d16 = (const uint4*)dinh;
        const uint4* h16 = (const uint4*)h0h;
        float s = dbih0[tid] + dbhh0[tid];
#pragma unroll 5
        for (int k8 = 0; k8 < 35; k8++) {
            uint4 w = wi[k8 * 1024 + tid]; uint4 v = d16[k8];
            s = dot2u(w.x, v.x, s); s = dot2u(w.y, v.y, s);
            s = dot2u(w.z, v.z, s); s = dot2u(w.w, v.w, s);
        }
#pragma unroll 8
        for (int k8 = 0; k8 < 32; k8++) {
            uint4 w = wh[k8 * 1024 + tid]; uint4 v = h16[k8];
            s = dot2u(w.x, v.x, s); s = dot2u(w.y, v.y, s);
            s = dot2u(w.z, v.z, s); s = dot2u(w.w, v.w, s);
        }
        comb[tid] = s;
    }
    __syncthreads();
    if (tid < 256) {
        float i = sigm(comb[tid]), f = sigm(comb[256 + tid]);
        float gg = tanhf(comb[512 + tid]), o = sigm(comb[768 + tid]);
        float c = f * c0r + i * gg;
        dc0[b * 256 + tid] = c;
        float hn = o * tanhf(c);
        h0h[tid] = f2h(hn); dh0[b * 256 + tid] = hn;
    }
    __syncthreads();
    // cell1
    {
        const uint4* wi = (const uint4*)pdWih1h;
        const uint4* wh = (const uint4*)pdWhh1h;
        const uint4* a16 = (const uint4*)h0h;
        const uint4* h16 = (const uint4*)h1h;
        float s = dbih1[tid] + dbhh1[tid];
#pragma unroll 8
        for (int k8 = 0; k8 < 32; k8++) {
            uint4 w = wi[k8 * 1024 + tid]; uint4 v = a16[k8];
            s = dot2u(w.x, v.x, s); s = dot2u(w.y, v.y, s);
            s = dot2u(w.z, v.z, s); s = dot2u(w.w, v.w, s);
        }
#pragma unroll 8
        for (int k8 = 0; k8 < 32; k8++) {
            uint4 w = wh[k8 * 1024 + tid]; uint4 v = h16[k8];
            s = dot2u(w.x, v.x, s); s = dot2u(w.y, v.y, s);
            s = dot2u(w.z, v.z, s); s = dot2u(w.w, v.w, s);
        }
        comb[tid] = s;
    }
    __syncthreads();
    if (tid < 256) {
        float i = sigm(comb[tid]), f = sigm(comb[256 + tid]);
        float gg = tanhf(comb[512 + tid]), o = sigm(comb[768 + tid]);
        float c = f * c1r + i * gg;
        dc1[b * 256 + tid] = c;
        float hn = o * tanhf(c);
        h1h[tid] = f2h(hn); dh1[b * 256 + tid] = hn;
    }
    __syncthreads();
    // out projection: r1 = relu(h1 @ Wo1^T + bo1), fp16 pair dot2
    {
        int o = tid & 255, q = tid >> 8;
        const unsigned int* wp = (const unsigned int*)pWo1Th;  // [128][256] pairs
        const unsigned int* hp = (const unsigned int*)h1h;     // 128 pairs
        float s = 0.f;
        for (int kk = q * 32; kk < q * 32 + 32; kk++)
            s = dot2u(wp[kk * 256 + o], hp[kk], s);
        comb[tid] = s;
    }
    __syncthreads();
    if (tid < 256) r1[tid] = fmaxf(bo1[tid] + comb[tid] + comb[256 + tid] + comb[512 + tid] + comb[768 + tid], 0.f);
    __syncthreads();
    if (tid < 256) {
        int o = tid >> 5, l = tid & 31;
        const float* wr = Wo2 + (size_t)o * 256;
        float s = 0.f;
#pragma unroll
        for (int m = 0; m < 8; m++) { int k = l + m * 32; s += r1[k] * wr[k]; }
        comb[tid] = s;
    }
    __syncthreads();
    if (tid < 8) {
        float s = bo2[tid];
        for (int l = 0; l < 32; l++) s += comb[tid * 32 + l];
        outp[((size_t)(b * T_LEN + t)) * 8 + tid] = s;
        ddin[b * 24 + 16 + tid] = s;
    }
    __syncthreads();
    // next-step qW, fp16 pair dot2
    {
        int n = tid & 255, q = tid >> 8;
        const unsigned int* wp = (const unsigned int*)pWaTh;   // [128][256] pairs
        const unsigned int* hp = (const unsigned int*)h1h;
        float s = 0.f;
        for (int kk = q * 32; kk < q * 32 + 32; kk++)
            s = dot2u(wp[kk * 256 + n], hp[kk], s);
        comb[tid] = s;
    }
    __syncthreads();
    if (tid < 256) dqW[b * 256 + tid] = comb[tid] + comb[256 + tid] + comb[512 + tid] + comb[768 + tid];
}

extern "C" void kernel_launch(void* const* d_in, const int* in_sizes, int n_in,
                              void* d_out, int out_size, void* d_ws, size_t ws_size,
                              hipStream_t stream) {
    static const int kExp[36] = {
        131072, 65536, 1,
        24576, 262144, 1024, 1024,
        24576, 262144, 1024, 1024,
        524288, 262144, 1024, 1024,
        524288, 262144, 1024, 1024,
        131072, 256,
        286720, 262144, 1024, 1024,
        262144, 262144, 1024, 1024,
        131072, 256, 256,
        65536, 256, 2048, 8
    };
    bool ok = (n_in == 36);
    if (ok) for (int i = 0; i < 36; i++) if (in_sizes[i] != kExp[i]) { ok = false; break; }
    if (!ok) { k_guard<<<(out_size + 255) / 256, 256, 0, stream>>>((float*)d_out, out_size, 0.05f); return; }
    if (out_size != 399360) { k_guard<<<(out_size + 255) / 256, 256, 0, stream>>>((float*)d_out, out_size, 0.07f); return; }
    if (ws_size < WS_NEED_BYTES) {
        float v = (float)(ws_size >> 20) * 1e-4f;
        k_guard<<<(out_size + 255) / 256, 256, 0, stream>>>((float*)d_out, out_size, v);
        return;
    }

    const float* x       = (const float*)d_in[0];
    const float* u       = (const float*)d_in[1];
    const float* eWih_f0 = (const float*)d_in[3];
    const float* eWhh_f0 = (const float*)d_in[4];
    const float* ebih_f0 = (const float*)d_in[5];
    const float* ebhh_f0 = (const float*)d_in[6];
    const float* eWih_b0 = (const float*)d_in[7];
    const float* eWhh_b0 = (const float*)d_in[8];
    const float* ebih_b0 = (const float*)d_in[9];
    const float* ebhh_b0 = (const float*)d_in[10];
    const float* eWih_f1 = (const float*)d_in[11];
    const float* eWhh_f1 = (const float*)d_in[12];
    const float* ebih_f1 = (const float*)d_in[13];
    const float* ebhh_f1 = (const float*)d_in[14];
    const float* eWih_b1 = (const float*)d_in[15];
    const float* eWhh_b1 = (const float*)d_in[16];
    const float* ebih_b1 = (const float*)d_in[17];
    const float* ebhh_b1 = (const float*)d_in[18];
    const float* Wp      = (const float*)d_in[19];
    const float* bp      = (const float*)d_in[20];
    const float* dWih0   = (const float*)d_in[21];
    const float* dWhh0   = (const float*)d_in[22];
    const float* dbih0   = (const float*)d_in[23];
    const float* dbhh0   = (const float*)d_in[24];
    const float* dWih1   = (const float*)d_in[25];
    const float* dWhh1   = (const float*)d_in[26];
    const float* dbih1   = (const float*)d_in[27];
    const float* dbhh1   = (const float*)d_in[28];
    const float* Wa      = (const float*)d_in[29];
    const float* ba      = (const float*)d_in[30];
    const float* va      = (const float*)d_in[31];
    const float* Wo1     = (const float*)d_in[32];
    const float* bo1     = (const float*)d_in[33];
    const float* Wo2     = (const float*)d_in[34];
    const float* bo2     = (const float*)d_in[35];

    float* ws = (float*)d_ws;
    float* A      = ws;
    float* enc    = ws;
    float* EpTmp  = ws + 2097152;
    float* Ept    = ws + 4194304;
    float* dh0    = ws + 12582912;
    float* dc0    = ws + 12587008;
    float* dh1    = ws + 12591104;
    float* dc1    = ws + 12595200;
    float* ddin   = ws + 12599296;
    float* dqW    = ws + 12599808;
    float* de     = ws + 12603904;
    float* dpsum  = ws + 12612096;
    float* dpctx  = ws + 12612224;
    float* y      = ws + 16777216;
    float* hb     = ws + 20971520;
    float* cb     = ws + 20975616;
    float* inp    = ws + 20979712;
    unsigned short* phk0f   = (unsigned short*)(ws + 21176320);
    unsigned short* pWo1Th  = (unsigned short*)(ws + 21307392);
    unsigned short* phk0b   = (unsigned short*)(ws + 21438464);
    unsigned short* pWaTh   = (unsigned short*)(ws + 21569536);
    unsigned short* phk1f   = (unsigned short*)(ws + 21700608);
    unsigned short* phk1b   = (unsigned short*)(ws + 21962752);
    unsigned short* pdWih0h = (unsigned short*)(ws + 22224896);
    unsigned short* pdWhh0h = (unsigned short*)(ws + 22511616);
    unsigned short* pdWih1h = (unsigned short*)(ws + 22773760);
    unsigned short* pdWhh1h = (unsigned short*)(ws + 23035904);
    float* pWaT   = ws + 23363584;

    // packing
    k_inp<<<768, 256, 0, stream>>>(x, u, inp);
    k_packh<<<1024, 256, 0, stream>>>(eWhh_f0, phk0f, 256);
    k_packh<<<1024, 256, 0, stream>>>(eWhh_b0, phk0b, 256);
    k_packh<<<1024, 256, 0, stream>>>(eWhh_f1, phk1f, 256);
    k_packh<<<1024, 256, 0, stream>>>(eWhh_b1, phk1b, 256);
    k_packh<<<1120, 256, 0, stream>>>(dWih0, pdWih0h, 280);
    k_packh<<<1024, 256, 0, stream>>>(dWhh0, pdWhh0h, 256);
    k_packh<<<1024, 256, 0, stream>>>(dWih1, pdWih1h, 256);
    k_packh<<<1024, 256, 0, stream>>>(dWhh1, pdWhh1h, 256);
    k_trT<<<256, 256, 0, stream>>>(Wa, 512, pWaT);
    k_trTh<<<256, 256, 0, stream>>>(Wa, 512, pWaTh);
    k_trTh<<<256, 256, 0, stream>>>(Wo1, 256, pWo1Th);

    // encoder
    k_ngemm<<<32768, 256, 0, stream>>>(inp, 24, eWih_f0, 24, ebih_f0, ebhh_f0, A, 8192, 1024, 24);
    k_ngemm<<<32768, 256, 0, stream>>>(inp, 24, eWih_b0, 24, ebih_b0, ebhh_b0, A + 8388608, 8192, 1024, 24);
    k_recL<<<dim3(16, 2), 1024, 0, stream>>>(A, phk0f, phk0b, y, nullptr, nullptr);
    k_gemm<<<dim3(128, 16), 256, 0, stream>>>(y, 512, eWih_f1, 512, 0, ebih_f1, ebhh_f1, A, 1024, 512);
    k_gemm<<<dim3(128, 16), 256, 0, stream>>>(y, 512, eWih_b1, 512, 0, ebih_b1, ebhh_b1, A + 8388608, 1024, 512);
    k_recL<<<dim3(16, 2), 1024, 0, stream>>>(A, phk1f, phk1b, y, hb, cb);
    k_gemm<<<dim3(128, 4), 256, 0, stream>>>(y, 512, Wp, 512, 0, bp, nullptr, enc, 256, 512);
    k_gemm<<<dim3(128, 4), 256, 0, stream>>>(enc, 256, Wa, 512, 256, ba, nullptr, EpTmp, 256, 256);
    k_trEp<<<8192, 256, 0, stream>>>(EpTmp, Ept);

    // decoder
    d_init<<<16, 256, 0, stream>>>(x, u, hb, cb, pWaT, dh0, dc0, dh1, dc1, ddin, dqW);
    for (int t = 0; t < T_LEN; t++) {
        d_attn<<<dim3(16, 8), 256, 0, stream>>>(Ept, enc, dqW, va, de, dpsum, dpctx);
        d_step<<<16, 1024, 0, stream>>>(de, dpsum, dpctx, ddin, dh0, dc0, dh1, dc1, dqW,
                                        pdWih0h, pdWhh0h, dbih0, dbhh0,
                                        pdWih1h, pdWhh1h, dbih1, dbhh1,
                                        pWo1Th, bo1, Wo2, bo2, pWaTh, t, (float*)d_out);
    }
}